// Round 11
// baseline (325.132 us; speedup 1.0000x reference)
//
#include <hip/hip_runtime.h>
#include <hip/hip_fp16.h>

#define NN 100000
#define NE 1600000
#define D 128
#define NC 8
#define NBUCK 391    // ceil(NN / 256) buckets of 256 node-ids
#define BCAP 6144    // fixed bucket capacity (mean 4092, sigma ~64 -> huge margin)
#define CHUNK 16384  // edges per binning block (98 blocks; hidden under gemm1)
#define NBLK_SC ((NE + CHUNK - 1) / CHUNK)  // 98

typedef _Float16 half8 __attribute__((ext_vector_type(8)));
typedef float f32x4 __attribute__((ext_vector_type(4)));

// ---------------- K1: weight cvt+transpose (blocks 0,1) + degree count (rest) ----
__global__ __launch_bounds__(256) void k_prep(const float* __restrict__ W1,
                                              __half* __restrict__ wt1,
                                              const float* __restrict__ W2,
                                              __half* __restrict__ wt2,
                                              const int* __restrict__ dst,
                                              int* __restrict__ cnt, int E) {
    const int t = threadIdx.x;
    if (blockIdx.x < 2) {  // wt[col][k] = half(W[k][col])
        const float* W = blockIdx.x ? W2 : W1;
        __half* wt = blockIdx.x ? wt2 : wt1;
        for (int i = t; i < D * D; i += 256) {
            int k = i >> 7, c = i & 127;
            wt[c * D + k] = __float2half(W[i]);
        }
        return;
    }
    int e0 = (blockIdx.x - 2) * 1024 + t * 4;
    if (e0 < E) {  // E % 4 == 0 -> full int4 safe
        int4 d4 = *(const int4*)&dst[e0];
        atomicAdd(&cnt[d4.x], 1);
        atomicAdd(&cnt[d4.y], 1);
        atomicAdd(&cnt[d4.z], 1);
        atomicAdd(&cnt[d4.w], 1);
    }
}

// ---------------- shared gemm body: hout[r] = half((A[r] @ W) * rsqrt(cnt[r]+1)) --
// 4 waves/block; wave = 16 rows x 64 cols (4 col-tiles x 4 K-steps of 16x16x32).
template <bool F32IN>
__device__ __forceinline__ void gemm_body(const void* __restrict__ Ain,
                                          const __half* __restrict__ wt,
                                          const int* __restrict__ cnt,
                                          __half* __restrict__ hout, int gb) {
    const int tid = threadIdx.x;
    const int lane = tid & 63;
    const int wave = tid >> 6;
    const int wr = wave >> 1, wc = wave & 1;
    const int row0 = gb * 32 + wr * 16;
    const int arow = row0 + (lane & 15);
    const int kg = lane >> 4;

    half8 afrag[4];
    if constexpr (F32IN) {
        const float* A = (const float*)Ain;
#pragma unroll
        for (int s = 0; s < 4; ++s) {
            const float* p = &A[(size_t)arow * D + s * 32 + kg * 8];
            float4 f0 = *(const float4*)p;
            float4 f1 = *(const float4*)(p + 4);
            half8 a;
            a[0] = (_Float16)f0.x; a[1] = (_Float16)f0.y;
            a[2] = (_Float16)f0.z; a[3] = (_Float16)f0.w;
            a[4] = (_Float16)f1.x; a[5] = (_Float16)f1.y;
            a[6] = (_Float16)f1.z; a[7] = (_Float16)f1.w;
            afrag[s] = a;
        }
    } else {
        const __half* A = (const __half*)Ain;
#pragma unroll
        for (int s = 0; s < 4; ++s)
            afrag[s] = *(const half8*)&A[(size_t)arow * D + s * 32 + kg * 8];
    }

    f32x4 acc[4] = {};
    const int colbase = wc * 64;
#pragma unroll
    for (int c = 0; c < 4; ++c) {
        const int col = colbase + c * 16 + (lane & 15);
#pragma unroll
        for (int s = 0; s < 4; ++s) {
            half8 b = *(const half8*)&wt[col * D + s * 32 + kg * 8];
            acc[c] = __builtin_amdgcn_mfma_f32_16x16x32_f16(afrag[s], b, acc[c], 0, 0, 0);
        }
    }

#pragma unroll
    for (int r = 0; r < 4; ++r) {
        const int row = row0 + kg * 4 + r;
        const float dv = rsqrtf((float)(cnt[row] + 1));
#pragma unroll
        for (int c = 0; c < 4; ++c) {
            const int col = colbase + c * 16 + (lane & 15);
            hout[(size_t)row * D + col] = __float2half(acc[c][r] * dv);
        }
    }
}

// ---------------- K2 mega-kernel: bscatter (blocks 0..97) || gemm1 (rest) --------
// bscatter: staged[b*BCAP+pos] = src*256 | (dst&255); two passes over its chunk
// (histogram -> block-reserve -> scatter), re-reading edges (L2-hot) to cap VGPRs.
__global__ __launch_bounds__(256) void k_work(const int* __restrict__ src,
                                              const int* __restrict__ dst,
                                              int* __restrict__ bcursor,
                                              int* __restrict__ staged,
                                              const float* __restrict__ x,
                                              const __half* __restrict__ wt1,
                                              const int* __restrict__ cnt,
                                              __half* __restrict__ hout, int E) {
    if (blockIdx.x < NBLK_SC) {
        __shared__ int h[NBUCK];
        __shared__ int cur[NBUCK];
        const int t = threadIdx.x;
        for (int i = t; i < NBUCK; i += 256) h[i] = 0;
        __syncthreads();
        const int base0 = blockIdx.x * CHUNK;
#pragma unroll
        for (int i = 0; i < CHUNK / 1024; ++i) {
            int e = base0 + i * 1024 + t * 4;
            if (e < E) {
                int4 d4 = *(const int4*)&dst[e];
                atomicAdd(&h[d4.x >> 8], 1);
                atomicAdd(&h[d4.y >> 8], 1);
                atomicAdd(&h[d4.z >> 8], 1);
                atomicAdd(&h[d4.w >> 8], 1);
            }
        }
        __syncthreads();
        for (int i = t; i < NBUCK; i += 256) {
            int c = h[i];
            cur[i] = c ? (i * BCAP + atomicAdd(&bcursor[i], c)) : 0;
        }
        __syncthreads();
#pragma unroll
        for (int i = 0; i < CHUNK / 1024; ++i) {
            int e = base0 + i * 1024 + t * 4;
            if (e < E) {
                int4 d4 = *(const int4*)&dst[e];  // L2-hot re-read
                int4 s4 = *(const int4*)&src[e];
                int p;
                p = atomicAdd(&cur[d4.x >> 8], 1); staged[p] = s4.x * 256 + (d4.x & 255);
                p = atomicAdd(&cur[d4.y >> 8], 1); staged[p] = s4.y * 256 + (d4.y & 255);
                p = atomicAdd(&cur[d4.z >> 8], 1); staged[p] = s4.z * 256 + (d4.z & 255);
                p = atomicAdd(&cur[d4.w >> 8], 1); staged[p] = s4.w * 256 + (d4.w & 255);
            }
        }
        return;
    }
    gemm_body<true>(x, wt1, cnt, hout, blockIdx.x - NBLK_SC);
}

// ---------------- K3: per-bucket CSR build (reads cnt; staged read ONCE) ----------
__global__ __launch_bounds__(256) void k_bfill(const int* __restrict__ staged,
                                               const int* __restrict__ bcursor,
                                               const int* __restrict__ cnt,
                                               int* __restrict__ rowstart,
                                               int* __restrict__ csr) {
    const int b = blockIdx.x;
    const int t = threadIdx.x;
    const int bs = b * BCAP;
    const int be = bs + bcursor[b];
    __shared__ int ls[256];  // per-node global csr start
    __shared__ int sd[256];  // scan temp
    __shared__ int lc[256];  // per-node cursor
    const int node = (b << 8) + t;
    int v = (node < NN) ? cnt[node] : 0;
    sd[t] = v;
    __syncthreads();
    for (int off = 1; off < 256; off <<= 1) {
        int y = (t >= off) ? sd[t - off] : 0;
        __syncthreads();
        sd[t] += y;
        __syncthreads();
    }
    int ex = sd[t] - v;
    ls[t] = bs + ex;
    if (node < NN) rowstart[node] = bs + ex;
    lc[t] = 0;
    __syncthreads();
    for (int i = bs + t; i < be; i += 256) {
        int e = staged[i];
        int li = e & 255;
        int p = atomicAdd(&lc[li], 1);
        csr[ls[li] + p] = e >> 8;
    }
}

// ---------------- standalone gemm (layer 2) ----------------
__global__ __launch_bounds__(256) void k_gemm2(const __half* __restrict__ A,
                                               const __half* __restrict__ wt,
                                               const int* __restrict__ cnt,
                                               __half* __restrict__ hout) {
    gemm_body<false>(A, wt, cnt, hout, blockIdx.x);
}

__device__ inline void add8h(float* acc, float4 raw) {
    const __half2* hp = (const __half2*)&raw;
#pragma unroll
    for (int q = 0; q < 4; ++q) {
        float2 f = __half22float2(hp[q]);
        acc[2 * q] += f.x;
        acc[2 * q + 1] += f.y;
    }
}

// ---------------- aggregation: row-major fp16 gather, one wave per node ----------
// 16 lanes x 16B cover a 128-half row; 4 neighbor-groups; prefetch 8 rows/group
// before accumulating (32 rows in flight/wave). out = relu(dv*(self+sum)+b),
// dv = rsqrt(cnt+1) computed inline (no dinv array).
__global__ __launch_bounds__(256) void k_agg(const __half* __restrict__ hs,
                                             const int* __restrict__ rowstart,
                                             const int* __restrict__ cnt,
                                             const int* __restrict__ csr_src,
                                             const float* __restrict__ bias,
                                             __half* __restrict__ hout) {
    const int node = blockIdx.x * 4 + (threadIdx.x >> 6);  // NN % 4 == 0, exact grid
    const int lane = threadIdx.x & 63;
    const int g = lane >> 4;           // neighbor group 0..3
    const int f8 = (lane & 15) << 3;   // feature offset (8 halves = 16B per lane)

    float acc[8] = {};
    if (g == 0) add8h(acc, *(const float4*)&hs[(size_t)node * D + f8]);  // self-loop

    const int c = cnt[node];
    const int* __restrict__ cl = csr_src + rowstart[node];

    // group g owns neighbors g, g+4, g+8, ...; prefetch 8 per pass
    int t = g;
    while (t < c) {
        float4 v[8];
#pragma unroll
        for (int i = 0; i < 8; ++i) {
            int tt = t + 4 * i;
            if (tt < c) {
                int s = cl[tt];
                v[i] = *(const float4*)&hs[(size_t)s * D + f8];
            }
        }
#pragma unroll
        for (int i = 0; i < 8; ++i) {
            int tt = t + 4 * i;
            if (tt < c) add8h(acc, v[i]);
        }
        t += 32;
    }

    // combine the 4 groups
#pragma unroll
    for (int q = 0; q < 8; ++q) {
        acc[q] += __shfl_xor(acc[q], 16);
        acc[q] += __shfl_xor(acc[q], 32);
    }

    if (g == 0) {
        const float dv = rsqrtf((float)(c + 1));
        float r[8];
#pragma unroll
        for (int q = 0; q < 8; ++q) r[q] = fmaxf(fmaf(dv, acc[q], bias[f8 + q]), 0.f);
        union { float4 f; __half2 h[4]; } u;
#pragma unroll
        for (int q = 0; q < 4; ++q) u.h[q] = __floats2half2_rn(r[2 * q], r[2 * q + 1]);
        *(float4*)&hout[(size_t)node * D + f8] = u.f;
    }
}

// ---------------- output: softmax(h @ Wout + bout), fp16 h ----------------
__global__ void k_out(const __half* __restrict__ h, const float* __restrict__ Wout,
                      const float* __restrict__ bout, float* __restrict__ out, int n) {
    __shared__ float ws[D * NC];
    int tid = threadIdx.x;
    for (int i = tid; i < D * NC; i += 256) ws[i] = Wout[i];
    __syncthreads();
    int node = blockIdx.x * 32 + (tid >> 3);
    int c = tid & 7;
    if (node >= n) return;
    float acc = bout[c];
    const __half* hrow = &h[(size_t)node * D];
#pragma unroll
    for (int k8 = 0; k8 < 16; ++k8) {
        float4 raw = *(const float4*)&hrow[k8 * 8];
        const __half2* hp = (const __half2*)&raw;
#pragma unroll
        for (int q = 0; q < 4; ++q) {
            float2 f = __half22float2(hp[q]);
            int k = k8 * 8 + 2 * q;
            acc += f.x * ws[k * NC + c] + f.y * ws[(k + 1) * NC + c];
        }
    }
    float m = acc;
#pragma unroll
    for (int off = 1; off < 8; off <<= 1) m = fmaxf(m, __shfl_xor(m, off));
    float e = __expf(acc - m);
    float ssum = e;
#pragma unroll
    for (int off = 1; off < 8; off <<= 1) ssum += __shfl_xor(ssum, off);
    out[(size_t)node * NC + c] = e / ssum;
}

// ---------------- launch ----------------
extern "C" void kernel_launch(void* const* d_in, const int* in_sizes, int n_in,
                              void* d_out, int out_size, void* d_ws, size_t ws_size,
                              hipStream_t stream) {
    const float* x    = (const float*)d_in[0];
    const int*   ei   = (const int*)d_in[1];   // [2][NE]: row 0 = src, row 1 = dst
    const float* W1   = (const float*)d_in[2];
    const float* b1   = (const float*)d_in[3];
    const float* W2   = (const float*)d_in[4];
    const float* b2   = (const float*)d_in[5];
    const float* Wout = (const float*)d_in[6];
    const float* bout = (const float*)d_in[7];
    float* out = (float*)d_out;

    size_t off = 0;
    char* base = (char*)d_ws;
    auto alloc = [&](size_t bytes) -> void* {
        void* p = base + off;
        off += (bytes + 255) & ~(size_t)255;
        return p;
    };
    int*    cnt      = (int*)alloc((size_t)NN * 4);
    int*    bcursor  = (int*)alloc((size_t)NBUCK * 4);       // adjacent to cnt
    int*    rowstart = (int*)alloc((size_t)NN * 4);
    int*    csr      = (int*)alloc((size_t)NBUCK * BCAP * 4);  // bucket-padded
    __half* wt1      = (__half*)alloc((size_t)D * D * 2);
    __half* wt2      = (__half*)alloc((size_t)D * D * 2);
    __half* h16a     = (__half*)alloc((size_t)NN * D * 2);  // gemm output (row-major)
    __half* h16f     = (__half*)alloc((size_t)NN * D * 2);  // agg1 output (row-major)
    __half* h16b     = (__half*)alloc((size_t)NN * D * 2);  // agg2 output (row-major)
    int*    staged   = (int*)alloc((size_t)NBUCK * BCAP * 4);  // packed bucket staging
    if (off > ws_size) return;  // workspace too small; fail visibly

    const int* src = ei;
    const int* dst = ei + NE;

    // zero cnt + bcursor (adjacent allocations -> single memset covers both)
    hipMemsetAsync(cnt, 0, ((size_t)NN * 4 + 255 & ~(size_t)255) + (size_t)NBUCK * 4,
                   stream);

    // K1: weight cvt (2 blocks) + degree count (1563 blocks)
    k_prep<<<2 + (NE / 4 + 255) / 256, 256, 0, stream>>>(W1, wt1, W2, wt2, dst, cnt, NE);

    // K2: bucket scatter (98 blocks) || gemm layer 1 (3125 blocks)
    k_work<<<NBLK_SC + NN / 32, 256, 0, stream>>>(src, dst, bcursor, staged,
                                                  x, wt1, cnt, h16a, NE);

    // K3: per-bucket CSR fill
    k_bfill<<<NBUCK, 256, 0, stream>>>(staged, bcursor, cnt, rowstart, csr);

    int agg_grid = NN / 4;  // 25000 exactly
    // layer 1 aggregation
    k_agg<<<agg_grid, 256, 0, stream>>>(h16a, rowstart, cnt, csr, b1, h16f);
    // layer 2
    k_gemm2<<<NN / 32, 256, 0, stream>>>(h16f, wt2, cnt, h16a);
    k_agg<<<agg_grid, 256, 0, stream>>>(h16a, rowstart, cnt, csr, b2, h16b);
    // output projection + softmax
    k_out<<<(NN + 31) / 32, 256, 0, stream>>>(h16b, Wout, bout, out, NN);
}

// Round 12
// 280.654 us; speedup vs baseline: 1.1585x; 1.1585x over previous
//
#include <hip/hip_runtime.h>
#include <hip/hip_fp16.h>

#define NN 100000
#define NE 1600000
#define D 128
#define NC 8
#define NBUCK 391    // ceil(NN / 256) buckets of 256 node-ids
#define BCAP 6144    // fixed bucket capacity (mean 4092, sigma ~64 -> huge margin)
#define CHUNK 16384  // edges per binning block (98 blocks; hidden under gemm1)
#define NBLK_SC ((NE + CHUNK - 1) / CHUNK)  // 98

typedef _Float16 half8 __attribute__((ext_vector_type(8)));
typedef float f32x4 __attribute__((ext_vector_type(4)));

// ---------------- weight cvt+transpose: wt[col][k] = half(W[k][col]) -------------
__global__ void k_cvtw(const float* __restrict__ W1, __half* __restrict__ wt1,
                       const float* __restrict__ W2, __half* __restrict__ wt2) {
    const float* W = blockIdx.x ? W2 : W1;
    __half* wt = blockIdx.x ? wt2 : wt1;
    for (int i = threadIdx.x; i < D * D; i += 256) {
        int k = i >> 7, c = i & 127;
        wt[c * D + k] = __float2half(W[i]);
    }
}

// ---------------- shared gemm body: hout[r] = half(A[r] @ W)  (UNSCALED) ---------
// 4 waves/block; wave = 16 rows x 64 cols (4 col-tiles x 4 K-steps of 16x16x32).
template <bool F32IN>
__device__ __forceinline__ void gemm_body(const void* __restrict__ Ain,
                                          const __half* __restrict__ wt,
                                          __half* __restrict__ hout, int gb) {
    const int tid = threadIdx.x;
    const int lane = tid & 63;
    const int wave = tid >> 6;
    const int wr = wave >> 1, wc = wave & 1;
    const int row0 = gb * 32 + wr * 16;
    const int arow = row0 + (lane & 15);
    const int kg = lane >> 4;

    half8 afrag[4];
    if constexpr (F32IN) {
        const float* A = (const float*)Ain;
#pragma unroll
        for (int s = 0; s < 4; ++s) {
            const float* p = &A[(size_t)arow * D + s * 32 + kg * 8];
            float4 f0 = *(const float4*)p;
            float4 f1 = *(const float4*)(p + 4);
            half8 a;
            a[0] = (_Float16)f0.x; a[1] = (_Float16)f0.y;
            a[2] = (_Float16)f0.z; a[3] = (_Float16)f0.w;
            a[4] = (_Float16)f1.x; a[5] = (_Float16)f1.y;
            a[6] = (_Float16)f1.z; a[7] = (_Float16)f1.w;
            afrag[s] = a;
        }
    } else {
        const __half* A = (const __half*)Ain;
#pragma unroll
        for (int s = 0; s < 4; ++s)
            afrag[s] = *(const half8*)&A[(size_t)arow * D + s * 32 + kg * 8];
    }

    f32x4 acc[4] = {};
    const int colbase = wc * 64;
#pragma unroll
    for (int c = 0; c < 4; ++c) {
        const int col = colbase + c * 16 + (lane & 15);
#pragma unroll
        for (int s = 0; s < 4; ++s) {
            half8 b = *(const half8*)&wt[col * D + s * 32 + kg * 8];
            acc[c] = __builtin_amdgcn_mfma_f32_16x16x32_f16(afrag[s], b, acc[c], 0, 0, 0);
        }
    }

#pragma unroll
    for (int r = 0; r < 4; ++r) {
        const int row = row0 + kg * 4 + r;
#pragma unroll
        for (int c = 0; c < 4; ++c) {
            const int col = colbase + c * 16 + (lane & 15);
            hout[(size_t)row * D + col] = __float2half(acc[c][r]);
        }
    }
}

// ---------------- K2 mega-kernel: bscatter (blocks 0..97) || gemm1 (rest) --------
// These are INDEPENDENT (gemm1 no longer needs dinv). staged[b*BCAP+pos] =
// src*256 | (dst&255); two passes over the chunk (histogram -> reserve -> scatter).
__global__ __launch_bounds__(256) void k_work(const int* __restrict__ src,
                                              const int* __restrict__ dst,
                                              int* __restrict__ bcursor,
                                              int* __restrict__ staged,
                                              const float* __restrict__ x,
                                              const __half* __restrict__ wt1,
                                              __half* __restrict__ hout, int E) {
    if (blockIdx.x < NBLK_SC) {
        __shared__ int h[NBUCK];
        __shared__ int cur[NBUCK];
        const int t = threadIdx.x;
        for (int i = t; i < NBUCK; i += 256) h[i] = 0;
        __syncthreads();
        const int base0 = blockIdx.x * CHUNK;
#pragma unroll
        for (int i = 0; i < CHUNK / 1024; ++i) {
            int e = base0 + i * 1024 + t * 4;
            if (e < E) {  // E % 4 == 0 -> full int4 safe
                int4 d4 = *(const int4*)&dst[e];
                atomicAdd(&h[d4.x >> 8], 1);
                atomicAdd(&h[d4.y >> 8], 1);
                atomicAdd(&h[d4.z >> 8], 1);
                atomicAdd(&h[d4.w >> 8], 1);
            }
        }
        __syncthreads();
        for (int i = t; i < NBUCK; i += 256) {
            int c = h[i];
            cur[i] = c ? (i * BCAP + atomicAdd(&bcursor[i], c)) : 0;
        }
        __syncthreads();
#pragma unroll
        for (int i = 0; i < CHUNK / 1024; ++i) {
            int e = base0 + i * 1024 + t * 4;
            if (e < E) {
                int4 d4 = *(const int4*)&dst[e];  // L2-hot re-read
                int4 s4 = *(const int4*)&src[e];
                int p;
                p = atomicAdd(&cur[d4.x >> 8], 1); staged[p] = s4.x * 256 + (d4.x & 255);
                p = atomicAdd(&cur[d4.y >> 8], 1); staged[p] = s4.y * 256 + (d4.y & 255);
                p = atomicAdd(&cur[d4.z >> 8], 1); staged[p] = s4.z * 256 + (d4.z & 255);
                p = atomicAdd(&cur[d4.w >> 8], 1); staged[p] = s4.w * 256 + (d4.w & 255);
            }
        }
        return;
    }
    gemm_body<true>(x, wt1, hout, blockIdx.x - NBLK_SC);
}

// ---------------- K3: per-bucket CSR build (LDS histogram; r10-proven) ------------
// Emits rowstart, cnt, dinv (coalesced); csr fill in bucket-local L2 region.
__global__ __launch_bounds__(256) void k_bfill(const int* __restrict__ staged,
                                               const int* __restrict__ bcursor,
                                               int* __restrict__ rowstart,
                                               int* __restrict__ cnt,
                                               float* __restrict__ dinv,
                                               int* __restrict__ csr) {
    const int b = blockIdx.x;
    const int t = threadIdx.x;
    const int bs = b * BCAP;
    const int be = bs + bcursor[b];
    __shared__ int lc[256];  // per-node count, later reused as cursor
    __shared__ int ls[256];  // per-node global csr start
    __shared__ int sd[256];  // scan temp
    lc[t] = 0;
    __syncthreads();
    for (int i = bs + t; i < be; i += 256) {
        atomicAdd(&lc[staged[i] & 255], 1);
    }
    __syncthreads();
    int v = lc[t];
    sd[t] = v;
    __syncthreads();
    for (int off = 1; off < 256; off <<= 1) {
        int y = (t >= off) ? sd[t - off] : 0;
        __syncthreads();
        sd[t] += y;
        __syncthreads();
    }
    int ex = sd[t] - v;
    ls[t] = bs + ex;
    int node = (b << 8) + t;
    if (node < NN) {
        rowstart[node] = bs + ex;
        cnt[node] = v;
        dinv[node] = rsqrtf((float)(v + 1));  // +1 = self-loop
    }
    lc[t] = 0;  // reuse as cursor
    __syncthreads();
    for (int i = bs + t; i < be; i += 256) {
        int e = staged[i];
        int li = e & 255;
        int p = atomicAdd(&lc[li], 1);
        csr[ls[li] + p] = e >> 8;
    }
}

// ---------------- standalone gemm (layer 2) ----------------
__global__ __launch_bounds__(256) void k_gemm2(const __half* __restrict__ A,
                                               const __half* __restrict__ wt,
                                               __half* __restrict__ hout) {
    gemm_body<false>(A, wt, hout, blockIdx.x);
}

__device__ inline void fma8h(float* acc, float4 raw, float s) {
    const __half2* hp = (const __half2*)&raw;
#pragma unroll
    for (int q = 0; q < 4; ++q) {
        float2 f = __half22float2(hp[q]);
        acc[2 * q] = fmaf(s, f.x, acc[2 * q]);
        acc[2 * q + 1] = fmaf(s, f.y, acc[2 * q + 1]);
    }
}

// ---------------- aggregation: per-neighbor dinv[s] scale via fma ----------------
// h is UNSCALED; acc = dinv[i]*h[i] + sum_s dinv[s]*h[s] (fma = same VALU count as
// add; dinv[s] is a broadcast 4B L2-hot load). out = relu(dinv[i]*acc + b).
// 16 lanes x 16B cover a row; 4 groups; prefetch 8 rows+scales per pass.
__global__ __launch_bounds__(256) void k_agg(const __half* __restrict__ hs,
                                             const int* __restrict__ rowstart,
                                             const int* __restrict__ cnt,
                                             const int* __restrict__ csr_src,
                                             const float* __restrict__ dinv,
                                             const float* __restrict__ bias,
                                             __half* __restrict__ hout) {
    const int node = blockIdx.x * 4 + (threadIdx.x >> 6);  // NN % 4 == 0, exact grid
    const int lane = threadIdx.x & 63;
    const int g = lane >> 4;           // neighbor group 0..3
    const int f8 = (lane & 15) << 3;   // feature offset (8 halves = 16B per lane)

    const float dvn = dinv[node];
    float acc[8] = {};
    if (g == 0)  // self-loop: dinv[i]*h[i]
        fma8h(acc, *(const float4*)&hs[(size_t)node * D + f8], dvn);

    const int c = cnt[node];
    const int* __restrict__ cl = csr_src + rowstart[node];

    // group g owns neighbors g, g+4, g+8, ...; prefetch 8 rows + scales per pass
    int t = g;
    while (t < c) {
        float4 v[8];
        float dv8[8];
#pragma unroll
        for (int i = 0; i < 8; ++i) {
            int tt = t + 4 * i;
            if (tt < c) {
                int s = cl[tt];
                v[i] = *(const float4*)&hs[(size_t)s * D + f8];
                dv8[i] = dinv[s];
            }
        }
#pragma unroll
        for (int i = 0; i < 8; ++i) {
            int tt = t + 4 * i;
            if (tt < c) fma8h(acc, v[i], dv8[i]);
        }
        t += 32;
    }

    // combine the 4 groups
#pragma unroll
    for (int q = 0; q < 8; ++q) {
        acc[q] += __shfl_xor(acc[q], 16);
        acc[q] += __shfl_xor(acc[q], 32);
    }

    if (g == 0) {
        float r[8];
#pragma unroll
        for (int q = 0; q < 8; ++q) r[q] = fmaxf(fmaf(dvn, acc[q], bias[f8 + q]), 0.f);
        union { float4 f; __half2 h[4]; } u;
#pragma unroll
        for (int q = 0; q < 4; ++q) u.h[q] = __floats2half2_rn(r[2 * q], r[2 * q + 1]);
        *(float4*)&hout[(size_t)node * D + f8] = u.f;
    }
}

// ---------------- output: softmax(h @ Wout + bout), fp16 h ----------------
__global__ void k_out(const __half* __restrict__ h, const float* __restrict__ Wout,
                      const float* __restrict__ bout, float* __restrict__ out, int n) {
    __shared__ float ws[D * NC];
    int tid = threadIdx.x;
    for (int i = tid; i < D * NC; i += 256) ws[i] = Wout[i];
    __syncthreads();
    int node = blockIdx.x * 32 + (tid >> 3);
    int c = tid & 7;
    if (node >= n) return;
    float acc = bout[c];
    const __half* hrow = &h[(size_t)node * D];
#pragma unroll
    for (int k8 = 0; k8 < 16; ++k8) {
        float4 raw = *(const float4*)&hrow[k8 * 8];
        const __half2* hp = (const __half2*)&raw;
#pragma unroll
        for (int q = 0; q < 4; ++q) {
            float2 f = __half22float2(hp[q]);
            int k = k8 * 8 + 2 * q;
            acc += f.x * ws[k * NC + c] + f.y * ws[(k + 1) * NC + c];
        }
    }
    float m = acc;
#pragma unroll
    for (int off = 1; off < 8; off <<= 1) m = fmaxf(m, __shfl_xor(m, off));
    float e = __expf(acc - m);
    float ssum = e;
#pragma unroll
    for (int off = 1; off < 8; off <<= 1) ssum += __shfl_xor(ssum, off);
    out[(size_t)node * NC + c] = e / ssum;
}

// ---------------- launch ----------------
extern "C" void kernel_launch(void* const* d_in, const int* in_sizes, int n_in,
                              void* d_out, int out_size, void* d_ws, size_t ws_size,
                              hipStream_t stream) {
    const float* x    = (const float*)d_in[0];
    const int*   ei   = (const int*)d_in[1];   // [2][NE]: row 0 = src, row 1 = dst
    const float* W1   = (const float*)d_in[2];
    const float* b1   = (const float*)d_in[3];
    const float* W2   = (const float*)d_in[4];
    const float* b2   = (const float*)d_in[5];
    const float* Wout = (const float*)d_in[6];
    const float* bout = (const float*)d_in[7];
    float* out = (float*)d_out;

    size_t off = 0;
    char* base = (char*)d_ws;
    auto alloc = [&](size_t bytes) -> void* {
        void* p = base + off;
        off += (bytes + 255) & ~(size_t)255;
        return p;
    };
    int*    cnt      = (int*)alloc((size_t)NN * 4);
    int*    rowstart = (int*)alloc((size_t)NN * 4);
    int*    bcursor  = (int*)alloc((size_t)NBUCK * 4);
    int*    csr      = (int*)alloc((size_t)NBUCK * BCAP * 4);  // bucket-padded
    float*  dinv     = (float*)alloc((size_t)NN * 4);
    __half* wt1      = (__half*)alloc((size_t)D * D * 2);
    __half* wt2      = (__half*)alloc((size_t)D * D * 2);
    __half* h16a     = (__half*)alloc((size_t)NN * D * 2);  // gemm output (row-major)
    __half* h16f     = (__half*)alloc((size_t)NN * D * 2);  // agg1 output (row-major)
    __half* h16b     = (__half*)alloc((size_t)NN * D * 2);  // agg2 output (row-major)
    int*    staged   = (int*)alloc((size_t)NBUCK * BCAP * 4);  // packed bucket staging
    if (off > ws_size) return;  // workspace too small; fail visibly

    const int* src = ei;
    const int* dst = ei + NE;

    hipMemsetAsync(bcursor, 0, (size_t)NBUCK * 4, stream);

    // weight prep (tiny, unblocks gemm1 inside k_work)
    k_cvtw<<<2, 256, 0, stream>>>(W1, wt1, W2, wt2);

    // K2: bucket scatter (98 blocks) || gemm layer 1 (3125 blocks) — independent
    k_work<<<NBLK_SC + NN / 32, 256, 0, stream>>>(src, dst, bcursor, staged,
                                                  x, wt1, h16a, NE);

    // K3: per-bucket CSR fill (+ cnt, dinv)
    k_bfill<<<NBUCK, 256, 0, stream>>>(staged, bcursor, rowstart, cnt, dinv, csr);

    int agg_grid = NN / 4;  // 25000 exactly
    // layer 1 aggregation (per-neighbor dinv scale)
    k_agg<<<agg_grid, 256, 0, stream>>>(h16a, rowstart, cnt, csr, dinv, b1, h16f);
    // layer 2
    k_gemm2<<<NN / 32, 256, 0, stream>>>(h16f, wt2, h16a);
    k_agg<<<agg_grid, 256, 0, stream>>>(h16a, rowstart, cnt, csr, dinv, b2, h16b);
    // output projection + softmax
    k_out<<<(NN + 31) / 32, 256, 0, stream>>>(h16b, Wout, bout, out, NN);
}

// Round 13
// 269.922 us; speedup vs baseline: 1.2045x; 1.0398x over previous
//
#include <hip/hip_runtime.h>
#include <hip/hip_fp16.h>

#define NN 100000
#define NE 1600000
#define D 128
#define NC 8
#define NBUCK 391   // ceil(NN / 256) buckets of 256 node-ids
#define BCAP 6144   // fixed bucket capacity (mean 4092, sigma ~64 -> huge margin)
#define CHUNK 4096  // edges per binning block
#define NBLK_SC ((NE + CHUNK - 1) / CHUNK)  // 391

typedef _Float16 half8 __attribute__((ext_vector_type(8)));
typedef float f32x4 __attribute__((ext_vector_type(4)));

// ---------------- K1: bucket scatter (blocks 0..390) + weight cvt (391,392) ------
// staged[b*BCAP + pos] = src*256 | (dst&255)
__global__ __launch_bounds__(256) void k_scat(const int* __restrict__ src,
                                              const int* __restrict__ dst,
                                              int* __restrict__ bcursor,
                                              int* __restrict__ staged,
                                              const float* __restrict__ W1,
                                              __half* __restrict__ wt1,
                                              const float* __restrict__ W2,
                                              __half* __restrict__ wt2, int E) {
    const int t = threadIdx.x;
    if (blockIdx.x >= NBLK_SC) {  // wt[col][k] = half(W[k][col])
        const float* W = (blockIdx.x - NBLK_SC) ? W2 : W1;
        __half* wt = (blockIdx.x - NBLK_SC) ? wt2 : wt1;
        for (int i = t; i < D * D; i += 256) {
            int k = i >> 7, c = i & 127;
            wt[c * D + k] = __float2half(W[i]);
        }
        return;
    }
    __shared__ int h[NBUCK];
    __shared__ int cur[NBUCK];
    for (int i = t; i < NBUCK; i += 256) h[i] = 0;
    __syncthreads();
    const int base0 = blockIdx.x * CHUNK;
    int4 d4[4], s4[4];
    bool val[4];
#pragma unroll
    for (int i = 0; i < 4; ++i) {
        int e = base0 + i * 1024 + t * 4;
        val[i] = e < E;  // E % 4 == 0 -> full int4 safe
        if (val[i]) {
            d4[i] = *(const int4*)&dst[e];
            s4[i] = *(const int4*)&src[e];
            atomicAdd(&h[d4[i].x >> 8], 1);
            atomicAdd(&h[d4[i].y >> 8], 1);
            atomicAdd(&h[d4[i].z >> 8], 1);
            atomicAdd(&h[d4[i].w >> 8], 1);
        }
    }
    __syncthreads();
    for (int i = t; i < NBUCK; i += 256) {
        int c = h[i];
        cur[i] = c ? (i * BCAP + atomicAdd(&bcursor[i], c)) : 0;
    }
    __syncthreads();
#pragma unroll
    for (int i = 0; i < 4; ++i) {
        if (val[i]) {
            int p;
            p = atomicAdd(&cur[d4[i].x >> 8], 1); staged[p] = s4[i].x * 256 + (d4[i].x & 255);
            p = atomicAdd(&cur[d4[i].y >> 8], 1); staged[p] = s4[i].y * 256 + (d4[i].y & 255);
            p = atomicAdd(&cur[d4[i].z >> 8], 1); staged[p] = s4[i].z * 256 + (d4[i].z & 255);
            p = atomicAdd(&cur[d4[i].w >> 8], 1); staged[p] = s4[i].w * 256 + (d4[i].w & 255);
        }
    }
}

// ---------------- shared gemm body ------------------------------------------------
// SCALE: multiply row by dinv[row] in epilogue (layer 2); else write raw (layer 1).
template <bool F32IN, bool SCALE>
__device__ __forceinline__ void gemm_body(const void* __restrict__ Ain,
                                          const __half* __restrict__ wt,
                                          const float* __restrict__ dinv,
                                          __half* __restrict__ hout, int gb) {
    const int tid = threadIdx.x;
    const int lane = tid & 63;
    const int wave = tid >> 6;
    const int wr = wave >> 1, wc = wave & 1;
    const int row0 = gb * 32 + wr * 16;
    const int arow = row0 + (lane & 15);
    const int kg = lane >> 4;

    half8 afrag[4];
    if constexpr (F32IN) {
        const float* A = (const float*)Ain;
#pragma unroll
        for (int s = 0; s < 4; ++s) {
            const float* p = &A[(size_t)arow * D + s * 32 + kg * 8];
            float4 f0 = *(const float4*)p;
            float4 f1 = *(const float4*)(p + 4);
            half8 a;
            a[0] = (_Float16)f0.x; a[1] = (_Float16)f0.y;
            a[2] = (_Float16)f0.z; a[3] = (_Float16)f0.w;
            a[4] = (_Float16)f1.x; a[5] = (_Float16)f1.y;
            a[6] = (_Float16)f1.z; a[7] = (_Float16)f1.w;
            afrag[s] = a;
        }
    } else {
        const __half* A = (const __half*)Ain;
#pragma unroll
        for (int s = 0; s < 4; ++s)
            afrag[s] = *(const half8*)&A[(size_t)arow * D + s * 32 + kg * 8];
    }

    f32x4 acc[4] = {};
    const int colbase = wc * 64;
#pragma unroll
    for (int c = 0; c < 4; ++c) {
        const int col = colbase + c * 16 + (lane & 15);
#pragma unroll
        for (int s = 0; s < 4; ++s) {
            half8 b = *(const half8*)&wt[col * D + s * 32 + kg * 8];
            acc[c] = __builtin_amdgcn_mfma_f32_16x16x32_f16(afrag[s], b, acc[c], 0, 0, 0);
        }
    }

#pragma unroll
    for (int r = 0; r < 4; ++r) {
        const int row = row0 + kg * 4 + r;
        float dv = 1.0f;
        if constexpr (SCALE) dv = dinv[row];
#pragma unroll
        for (int c = 0; c < 4; ++c) {
            const int col = colbase + c * 16 + (lane & 15);
            hout[(size_t)row * D + col] = __float2half(SCALE ? acc[c][r] * dv : acc[c][r]);
        }
    }
}

// ---------------- K2: bfill (blocks 0..390) || gemm1 unscaled (rest) -------------
// Independent: bfill consumes staged/bcursor; gemm1 consumes x/wt1 only.
__global__ __launch_bounds__(256) void k_fg(const int* __restrict__ staged,
                                            const int* __restrict__ bcursor,
                                            int* __restrict__ rowstart,
                                            int* __restrict__ cnt,
                                            float* __restrict__ dinv,
                                            int* __restrict__ csr,
                                            const float* __restrict__ x,
                                            const __half* __restrict__ wt1,
                                            __half* __restrict__ hout) {
    const int b = blockIdx.x;
    if (b >= NBUCK) {
        gemm_body<true, false>(x, wt1, nullptr, hout, b - NBUCK);
        return;
    }
    const int t = threadIdx.x;
    const int bs = b * BCAP;
    const int be = bs + bcursor[b];
    __shared__ int lc[256];  // per-node count, later reused as cursor
    __shared__ int ls[256];  // per-node global csr start
    __shared__ int sd[256];  // scan temp
    lc[t] = 0;
    __syncthreads();
    for (int i = bs + t; i < be; i += 256) {
        atomicAdd(&lc[staged[i] & 255], 1);
    }
    __syncthreads();
    int v = lc[t];
    sd[t] = v;
    __syncthreads();
    for (int off = 1; off < 256; off <<= 1) {
        int y = (t >= off) ? sd[t - off] : 0;
        __syncthreads();
        sd[t] += y;
        __syncthreads();
    }
    int ex = sd[t] - v;
    ls[t] = bs + ex;
    int node = (b << 8) + t;
    if (node < NN) {
        rowstart[node] = bs + ex;
        cnt[node] = v;
        dinv[node] = rsqrtf((float)(v + 1));  // +1 = self-loop
    }
    lc[t] = 0;  // reuse as cursor
    __syncthreads();
    for (int i = bs + t; i < be; i += 256) {
        int e = staged[i];
        int li = e & 255;
        int p = atomicAdd(&lc[li], 1);
        csr[ls[li] + p] = e >> 8;
    }
}

// ---------------- standalone gemm layer 2 (scaled epilogue) ----------------------
__global__ __launch_bounds__(256) void k_gemm2(const __half* __restrict__ A,
                                               const __half* __restrict__ wt,
                                               const float* __restrict__ dinv,
                                               __half* __restrict__ hout) {
    gemm_body<false, true>(A, wt, dinv, hout, blockIdx.x);
}

__device__ inline void add8h(float* acc, float4 raw) {
    const __half2* hp = (const __half2*)&raw;
#pragma unroll
    for (int q = 0; q < 4; ++q) {
        float2 f = __half22float2(hp[q]);
        acc[2 * q] += f.x;
        acc[2 * q + 1] += f.y;
    }
}

__device__ inline void fma8h(float* acc, float4 raw, float s) {
    const __half2* hp = (const __half2*)&raw;
#pragma unroll
    for (int q = 0; q < 4; ++q) {
        float2 f = __half22float2(hp[q]);
        acc[2 * q] = fmaf(s, f.x, acc[2 * q]);
        acc[2 * q + 1] = fmaf(s, f.y, acc[2 * q + 1]);
    }
}

// ---------------- agg layer 1: UNSCALED h; per-neighbor dinv[s] via fma ----------
__global__ __launch_bounds__(256) void k_agg_u(const __half* __restrict__ hs,
                                               const int* __restrict__ rowstart,
                                               const int* __restrict__ cnt,
                                               const int* __restrict__ csr_src,
                                               const float* __restrict__ dinv,
                                               const float* __restrict__ bias,
                                               __half* __restrict__ hout) {
    const int node = blockIdx.x * 4 + (threadIdx.x >> 6);  // NN % 4 == 0, exact grid
    const int lane = threadIdx.x & 63;
    const int g = lane >> 4;
    const int f8 = (lane & 15) << 3;

    const float dvn = dinv[node];
    float acc[8] = {};
    if (g == 0) fma8h(acc, *(const float4*)&hs[(size_t)node * D + f8], dvn);

    const int c = cnt[node];
    const int* __restrict__ cl = csr_src + rowstart[node];

    int t = g;
    while (t < c) {
        float4 v[8];
        float dv8[8];
#pragma unroll
        for (int i = 0; i < 8; ++i) {
            int tt = t + 4 * i;
            if (tt < c) {
                int s = cl[tt];
                v[i] = *(const float4*)&hs[(size_t)s * D + f8];
                dv8[i] = dinv[s];
            }
        }
#pragma unroll
        for (int i = 0; i < 8; ++i) {
            int tt = t + 4 * i;
            if (tt < c) fma8h(acc, v[i], dv8[i]);
        }
        t += 32;
    }

#pragma unroll
    for (int q = 0; q < 8; ++q) {
        acc[q] += __shfl_xor(acc[q], 16);
        acc[q] += __shfl_xor(acc[q], 32);
    }

    if (g == 0) {
        float r[8];
#pragma unroll
        for (int q = 0; q < 8; ++q) r[q] = fmaxf(fmaf(dvn, acc[q], bias[f8 + q]), 0.f);
        union { float4 f; __half2 h[4]; } u;
#pragma unroll
        for (int q = 0; q < 4; ++q) u.h[q] = __floats2half2_rn(r[2 * q], r[2 * q + 1]);
        *(float4*)&hout[(size_t)node * D + f8] = u.f;
    }
}

// ---------------- agg layer 2: PRE-SCALED h; plain adds (r10-proven, 67.5us) -----
__global__ __launch_bounds__(256) void k_agg_s(const __half* __restrict__ hs,
                                               const int* __restrict__ rowstart,
                                               const int* __restrict__ cnt,
                                               const int* __restrict__ csr_src,
                                               const float* __restrict__ dinv,
                                               const float* __restrict__ bias,
                                               __half* __restrict__ hout) {
    const int node = blockIdx.x * 4 + (threadIdx.x >> 6);
    const int lane = threadIdx.x & 63;
    const int g = lane >> 4;
    const int f8 = (lane & 15) << 3;

    float acc[8] = {};
    if (g == 0) add8h(acc, *(const float4*)&hs[(size_t)node * D + f8]);

    const int c = cnt[node];
    const int* __restrict__ cl = csr_src + rowstart[node];

    int t = g;
    while (t < c) {
        float4 v[8];
#pragma unroll
        for (int i = 0; i < 8; ++i) {
            int tt = t + 4 * i;
            if (tt < c) {
                int s = cl[tt];
                v[i] = *(const float4*)&hs[(size_t)s * D + f8];
            }
        }
#pragma unroll
        for (int i = 0; i < 8; ++i) {
            int tt = t + 4 * i;
            if (tt < c) add8h(acc, v[i]);
        }
        t += 32;
    }

#pragma unroll
    for (int q = 0; q < 8; ++q) {
        acc[q] += __shfl_xor(acc[q], 16);
        acc[q] += __shfl_xor(acc[q], 32);
    }

    if (g == 0) {
        const float dv = dinv[node];
        float r[8];
#pragma unroll
        for (int q = 0; q < 8; ++q) r[q] = fmaxf(fmaf(dv, acc[q], bias[f8 + q]), 0.f);
        union { float4 f; __half2 h[4]; } u;
#pragma unroll
        for (int q = 0; q < 4; ++q) u.h[q] = __floats2half2_rn(r[2 * q], r[2 * q + 1]);
        *(float4*)&hout[(size_t)node * D + f8] = u.f;
    }
}

// ---------------- output: softmax(h @ Wout + bout), fp16 h ----------------
__global__ void k_out(const __half* __restrict__ h, const float* __restrict__ Wout,
                      const float* __restrict__ bout, float* __restrict__ out, int n) {
    __shared__ float ws[D * NC];
    int tid = threadIdx.x;
    for (int i = tid; i < D * NC; i += 256) ws[i] = Wout[i];
    __syncthreads();
    int node = blockIdx.x * 32 + (tid >> 3);
    int c = tid & 7;
    if (node >= n) return;
    float acc = bout[c];
    const __half* hrow = &h[(size_t)node * D];
#pragma unroll
    for (int k8 = 0; k8 < 16; ++k8) {
        float4 raw = *(const float4*)&hrow[k8 * 8];
        const __half2* hp = (const __half2*)&raw;
#pragma unroll
        for (int q = 0; q < 4; ++q) {
            float2 f = __half22float2(hp[q]);
            int k = k8 * 8 + 2 * q;
            acc += f.x * ws[k * NC + c] + f.y * ws[(k + 1) * NC + c];
        }
    }
    float m = acc;
#pragma unroll
    for (int off = 1; off < 8; off <<= 1) m = fmaxf(m, __shfl_xor(m, off));
    float e = __expf(acc - m);
    float ssum = e;
#pragma unroll
    for (int off = 1; off < 8; off <<= 1) ssum += __shfl_xor(ssum, off);
    out[(size_t)node * NC + c] = e / ssum;
}

// ---------------- launch ----------------
extern "C" void kernel_launch(void* const* d_in, const int* in_sizes, int n_in,
                              void* d_out, int out_size, void* d_ws, size_t ws_size,
                              hipStream_t stream) {
    const float* x    = (const float*)d_in[0];
    const int*   ei   = (const int*)d_in[1];   // [2][NE]: row 0 = src, row 1 = dst
    const float* W1   = (const float*)d_in[2];
    const float* b1   = (const float*)d_in[3];
    const float* W2   = (const float*)d_in[4];
    const float* b2   = (const float*)d_in[5];
    const float* Wout = (const float*)d_in[6];
    const float* bout = (const float*)d_in[7];
    float* out = (float*)d_out;

    size_t off = 0;
    char* base = (char*)d_ws;
    auto alloc = [&](size_t bytes) -> void* {
        void* p = base + off;
        off += (bytes + 255) & ~(size_t)255;
        return p;
    };
    int*    cnt      = (int*)alloc((size_t)NN * 4);
    int*    rowstart = (int*)alloc((size_t)NN * 4);
    int*    bcursor  = (int*)alloc((size_t)NBUCK * 4);
    int*    csr      = (int*)alloc((size_t)NBUCK * BCAP * 4);  // bucket-padded
    float*  dinv     = (float*)alloc((size_t)NN * 4);
    __half* wt1      = (__half*)alloc((size_t)D * D * 2);
    __half* wt2      = (__half*)alloc((size_t)D * D * 2);
    __half* h16a     = (__half*)alloc((size_t)NN * D * 2);
    __half* h16f     = (__half*)alloc((size_t)NN * D * 2);
    __half* h16b     = (__half*)alloc((size_t)NN * D * 2);
    int*    staged   = (int*)alloc((size_t)NBUCK * BCAP * 4);
    if (off > ws_size) return;  // workspace too small; fail visibly

    const int* src = ei;
    const int* dst = ei + NE;

    hipMemsetAsync(bcursor, 0, (size_t)NBUCK * 4, stream);

    // K1: bucket scatter (391 blocks) + weight cvt (2 blocks)
    k_scat<<<NBLK_SC + 2, 256, 0, stream>>>(src, dst, bcursor, staged,
                                            W1, wt1, W2, wt2, NE);

    // K2: CSR fill (391 blocks) || gemm layer 1 unscaled (3125 blocks)
    k_fg<<<NBUCK + NN / 32, 256, 0, stream>>>(staged, bcursor, rowstart, cnt, dinv,
                                              csr, x, wt1, h16a);

    int agg_grid = NN / 4;  // 25000 exactly
    // layer 1 aggregation (per-neighbor dinv)
    k_agg_u<<<agg_grid, 256, 0, stream>>>(h16a, rowstart, cnt, csr, dinv, b1, h16f);
    // layer 2: scaled gemm, cheap agg
    k_gemm2<<<NN / 32, 256, 0, stream>>>(h16f, wt2, dinv, h16a);
    k_agg_s<<<agg_grid, 256, 0, stream>>>(h16a, rowstart, cnt, csr, dinv, b2, h16b);
    // output projection + softmax
    k_out<<<(NN + 31) / 32, 256, 0, stream>>>(h16b, Wout, bout, out, NN);
}